// Round 1
// baseline (6804.475 us; speedup 1.0000x reference)
//
#include <hip/hip_runtime.h>
#include <stdint.h>

// Encoder: embedding gather + xz GEMM + sequential LSTM (all-sigmoid) scan.
// B=64, T=256, E=512, UNITS=1024, gates 4*1024, gate order [i,f,g,o].

typedef __attribute__((ext_vector_type(8))) short short8;
typedef __attribute__((ext_vector_type(4))) float f32x4;

#define NB 64
#define NT 256
#define NE 512
#define NU 1024
#define NG 4096
#define ROWS (NB*NT)          // 16384

// workspace layout (bytes)
#define WS_EM    ((size_t)0)                      // em_bf16 [16384][512]
#define WS_WT    ((size_t)16777216)               // W^T bf16 [4096][512]
#define WS_UT    ((size_t)20971520)               // U^T bf16 [4096][1024]
#define WS_XZ    ((size_t)29360128)               // xz bf16 [16384][4096]
#define WS_HBUF  ((size_t)163577856)              // hbuf [2][4][16384] bf16
#define WS_FLAGS ((size_t)163840000)              // 256 x u32

#define SCAN_LDS_BYTES (131072 + 4352)

__device__ inline unsigned short f2bf(float x) {
    union { float f; uint32_t u; } v; v.f = x;
    uint32_t u = v.u;
    uint32_t r = u + 0x7FFFu + ((u >> 16) & 1u);   // RNE
    return (unsigned short)(r >> 16);
}
__device__ inline float bf2f(unsigned short h) {
    union { uint32_t u; float f; } v; v.u = ((uint32_t)h) << 16;
    return v.f;
}
__device__ inline float sigmoidf(float z) { return 1.f / (1.f + __expf(-z)); }

// ---------- cast + transpose: out[n*K+k] = bf16(in[k*N+n]) ----------
__global__ void __launch_bounds__(256) cast_transpose_kernel(
    const float* __restrict__ in, unsigned short* __restrict__ out,
    int kLog, int K, int N) {
    int idx = blockIdx.x * 256 + threadIdx.x;
    if (idx >= K * N) return;
    int n = idx >> kLog;
    int k = idx & (K - 1);
    out[idx] = f2bf(in[(size_t)k * N + n]);
}

// ---------- embedding gather + bf16 cast ----------
__global__ void __launch_bounds__(256) gather_kernel(
    const int* __restrict__ tokens, const float* __restrict__ emb,
    unsigned short* __restrict__ em) {
    int r = blockIdx.x;                      // 16384 rows = b*256+t
    int tok = tokens[r];
    const float* src = emb + (size_t)tok * NE;
    unsigned short* dst = em + (size_t)r * NE;
    for (int i = threadIdx.x; i < NE; i += 256) dst[i] = f2bf(src[i]);
}

// ---------- GEMM1: xz = em @ W + b   (A[16384][512] bf16, BT[4096][512] bf16) ----------
__global__ void __launch_bounds__(256) gemm1_kernel(
    const unsigned short* __restrict__ A, const unsigned short* __restrict__ BT,
    const float* __restrict__ bias, unsigned short* __restrict__ C) {
    __shared__ unsigned short As[128 * 64];
    __shared__ unsigned short Bs[128 * 64];
    int bid = blockIdx.x;
    int mb = bid & 127, nb = bid >> 7;       // 128 M-tiles x 32 N-tiles
    int tid = threadIdx.x;
    int w = tid >> 6, l = tid & 63;
    int wm = w >> 1, wn = w & 1;             // 64x64 quadrant per wave

    f32x4 acc[4][4];
#pragma unroll
    for (int i = 0; i < 4; i++)
#pragma unroll
        for (int j = 0; j < 4; j++) acc[i][j] = f32x4{0.f, 0.f, 0.f, 0.f};

    for (int kt = 0; kt < 8; ++kt) {         // K=512, BK=64
        short8 av[4], bv[4];
#pragma unroll
        for (int r = 0; r < 4; ++r) {
            int chunk = r * 256 + tid;       // 1024 chunks of 8 bf16
            int row = chunk >> 3, c8 = chunk & 7;
            av[r] = *(const short8*)(A + ((size_t)(mb * 128 + row)) * NE + kt * 64 + c8 * 8);
            bv[r] = *(const short8*)(BT + ((size_t)(nb * 128 + row)) * NE + kt * 64 + c8 * 8);
        }
#pragma unroll
        for (int r = 0; r < 4; ++r) {
            int chunk = r * 256 + tid;
            *(short8*)(As + chunk * 8) = av[r];
            *(short8*)(Bs + chunk * 8) = bv[r];
        }
        __syncthreads();
#pragma unroll
        for (int kk = 0; kk < 2; ++kk) {
            short8 af[4], bf[4];
#pragma unroll
            for (int mi = 0; mi < 4; ++mi)
                af[mi] = *(const short8*)(As + (wm * 64 + mi * 16 + (l & 15)) * 64 + kk * 32 + (l >> 4) * 8);
#pragma unroll
            for (int ni = 0; ni < 4; ++ni)
                bf[ni] = *(const short8*)(Bs + (wn * 64 + ni * 16 + (l & 15)) * 64 + kk * 32 + (l >> 4) * 8);
#pragma unroll
            for (int mi = 0; mi < 4; ++mi)
#pragma unroll
                for (int ni = 0; ni < 4; ++ni)
                    acc[mi][ni] = __builtin_amdgcn_mfma_f32_16x16x32_bf16(af[mi], bf[ni], acc[mi][ni], 0, 0, 0);
        }
        __syncthreads();
    }
    // epilogue: C = bf16(acc + bias)
#pragma unroll
    for (int ni = 0; ni < 4; ++ni) {
        int col = nb * 128 + wn * 64 + ni * 16 + (l & 15);
        float bvv = bias[col];
#pragma unroll
        for (int mi = 0; mi < 4; ++mi) {
#pragma unroll
            for (int r = 0; r < 4; ++r) {
                int row = mb * 128 + wm * 64 + mi * 16 + ((l >> 4) * 4) + r;
                C[(size_t)row * NG + col] = f2bf(acc[mi][ni][r] + bvv);
            }
        }
    }
}

// ---------- persistent LSTM scan ----------
// 256 blocks: p = wg>>6 (batch group of 16), q = wg&63 (16 units x 4 gates).
// U fragments LDS-resident; h exchanged via global hbuf (frag layout), flags per WG.
__global__ void __launch_bounds__(256) scan_kernel(
    const unsigned short* __restrict__ UT,   // [4096][1024] bf16 (n-major)
    const unsigned short* __restrict__ XZ,   // [16384][4096] bf16, row = b*256+t
    const float* __restrict__ h0, const float* __restrict__ c0,
    unsigned short* hbuf,                    // [2][4][16384] bf16
    unsigned int* flags,                     // [256]
    float* __restrict__ out) {
    extern __shared__ unsigned char smem[];
    unsigned short* Uf = (unsigned short*)smem;          // 65536 bf16 = 128 KB
    float* zbuf = (float*)(smem + 131072);               // [4][16][17] f32

    const int wg = blockIdx.x;
    const int p = wg >> 6, q = wg & 63;
    const int tid = threadIdx.x;
    const int g = tid >> 6;        // wave index == gate
    const int l = tid & 63;

    // ---- stage U fragments into LDS (one-time) ----
    // frag elem f = ((gate*32 + kt)*64 + grp*16 + cl)*8 + j  <=  UT[gate*1024+q*16+cl][kt*32+grp*8+j]
    for (int c = tid; c < 8192; c += 256) {
        int ln = c >> 7;                 // 0..63 local col (gate*16 + cl)
        int rem = c & 127;
        int kt = rem >> 2, grp = rem & 3;
        int gate = ln >> 4, cl = ln & 15;
        int ncol = gate * NU + q * 16 + cl;
        short8 v = *(const short8*)(UT + (size_t)ncol * NU + kt * 32 + grp * 8);
        *(short8*)(Uf + (size_t)((gate * 32 + kt) * 64 + grp * 16 + cl) * 8) = v;
    }

    // ---- per-thread ownership for gate combine: (batch-local, unit-local) ----
    const int bl = tid >> 4, ul = tid & 15;
    const int b = p * 16 + bl, u = q * 16 + ul;
    float c_reg = c0[(size_t)b * NU + u];
    {   // publish h0 into parity-0 buffer (fragment layout)
        float hv = h0[(size_t)b * NU + u];
        int kt = u >> 5, grp = (u >> 3) & 3, j = u & 7;
        hbuf[(size_t)p * 16384 + ((kt * 64 + grp * 16 + bl) * 8 + j)] = f2bf(hv);
    }
    __syncthreads();                       // drains vmem + LDS writes
    if (tid == 0)
        __hip_atomic_store(&flags[wg], 1u, __ATOMIC_RELEASE, __HIP_MEMORY_SCOPE_AGENT);

    const unsigned short* xz_base = XZ + (size_t)(p * 16) * NT * NG + (size_t)(g * NU + q * 16);
    float* outO = out;
    float* outH = out + (size_t)NB * NT * NU;
    float* outC = outH + (size_t)NB * NU;

    for (int s = 0; s < NT; ++s) {
        // wait for all 64 producers of my batch group
        if (tid < 64) {
            const unsigned int target = (unsigned int)(s + 1);
            unsigned int* f = &flags[p * 64 + tid];
            while (__hip_atomic_load(f, __ATOMIC_RELAXED, __HIP_MEMORY_SCOPE_AGENT) < target)
                __builtin_amdgcn_s_sleep(1);
        }
        __syncthreads();
        __threadfence();                   // acquire: L1 invalidate so hbuf reads are fresh

        const unsigned short* hb = hbuf + (size_t)((s & 1) * 4 + p) * 16384;
        f32x4 acc = f32x4{0.f, 0.f, 0.f, 0.f};
#pragma unroll 8
        for (int kt = 0; kt < 32; ++kt) {
            short8 af = *(const short8*)(hb + (kt * 64 + l) * 8);
            short8 bfg = *(const short8*)(Uf + ((g * 32 + kt) * 64 + l) * 8);
            acc = __builtin_amdgcn_mfma_f32_16x16x32_bf16(af, bfg, acc, 0, 0, 0);
        }
        {   // z = acc + xz  -> zbuf[gate][batch][unit]
            int rb0 = (l >> 4) * 4;
            int zc = l & 15;
#pragma unroll
            for (int r = 0; r < 4; ++r) {
                int bb = rb0 + r;
                float xv = bf2f(xz_base[(size_t)(bb * NT + s) * NG + zc]);
                zbuf[(g * 16 + bb) * 17 + zc] = acc[r] + xv;
            }
        }
        __syncthreads();
        {   // gate combine (thread owns (bl, ul))
            float zi = zbuf[(0 * 16 + bl) * 17 + ul];
            float zf = zbuf[(1 * 16 + bl) * 17 + ul];
            float zg = zbuf[(2 * 16 + bl) * 17 + ul];
            float zo = zbuf[(3 * 16 + bl) * 17 + ul];
            float gi = sigmoidf(zi), gf = sigmoidf(zf);
            float gg = sigmoidf(zg), go = sigmoidf(zo);
            c_reg = gf * c_reg + gi * gg;
            float h = go * sigmoidf(c_reg);
            outO[((size_t)b * NT + s) * NU + u] = h;
            int kt = u >> 5, grp = (u >> 3) & 3, j = u & 7;
            hbuf[(size_t)(((s + 1) & 1) * 4 + p) * 16384 + ((kt * 64 + grp * 16 + bl) * 8 + j)] = f2bf(h);
            if (s == NT - 1) {
                outH[(size_t)b * NU + u] = h;
                outC[(size_t)b * NU + u] = c_reg;
            }
        }
        __syncthreads();                   // drain h stores before publishing
        if (tid == 0)
            __hip_atomic_store(&flags[wg], (unsigned int)(s + 2), __ATOMIC_RELEASE, __HIP_MEMORY_SCOPE_AGENT);
    }
}

extern "C" void kernel_launch(void* const* d_in, const int* in_sizes, int n_in,
                              void* d_out, int out_size, void* d_ws, size_t ws_size,
                              hipStream_t stream) {
    const int* tokens = (const int*)d_in[0];
    const float* h0 = (const float*)d_in[1];
    const float* c0 = (const float*)d_in[2];
    const float* emb = (const float*)d_in[3];
    const float* W = (const float*)d_in[4];
    const float* U = (const float*)d_in[5];
    const float* bias = (const float*)d_in[6];
    float* out = (float*)d_out;

    unsigned char* ws = (unsigned char*)d_ws;
    unsigned short* em_bf = (unsigned short*)(ws + WS_EM);
    unsigned short* WT = (unsigned short*)(ws + WS_WT);
    unsigned short* UT = (unsigned short*)(ws + WS_UT);
    unsigned short* XZ = (unsigned short*)(ws + WS_XZ);
    unsigned short* hbuf = (unsigned short*)(ws + WS_HBUF);
    unsigned int* flags = (unsigned int*)(ws + WS_FLAGS);

    hipMemsetAsync(flags, 0, 1024, stream);

    {   // W [512][4096] -> WT [4096][512]
        int total = NE * NG;
        cast_transpose_kernel<<<(total + 255) / 256, 256, 0, stream>>>(W, WT, 9, NE, NG);
    }
    {   // U [1024][4096] -> UT [4096][1024]
        int total = NU * NG;
        cast_transpose_kernel<<<(total + 255) / 256, 256, 0, stream>>>(U, UT, 10, NU, NG);
    }
    gather_kernel<<<ROWS, 256, 0, stream>>>(tokens, emb, em_bf);
    gemm1_kernel<<<4096, 256, 0, stream>>>(em_bf, WT, bias, XZ);

    hipFuncSetAttribute((const void*)scan_kernel,
                        hipFuncAttributeMaxDynamicSharedMemorySize, SCAN_LDS_BYTES);
    scan_kernel<<<256, 256, SCAN_LDS_BYTES, stream>>>(UT, XZ, h0, c0, hbuf, flags, out);
}

// Round 2
// 2352.169 us; speedup vs baseline: 2.8929x; 2.8929x over previous
//
#include <hip/hip_runtime.h>
#include <stdint.h>

// Encoder: embedding gather + xz GEMM + sequential LSTM (all-sigmoid) scan.
// B=64, T=256, E=512, UNITS=1024, gates 4*1024, gate order [i,f,g,o].

typedef __attribute__((ext_vector_type(8))) short short8;
typedef __attribute__((ext_vector_type(4))) float f32x4;

#define NB 64
#define NT 256
#define NE 512
#define NU 1024
#define NG 4096
#define ROWS (NB*NT)          // 16384

// workspace layout (bytes)
#define WS_EM    ((size_t)0)                      // em_bf16 [16384][512]
#define WS_WT    ((size_t)16777216)               // W^T bf16 [4096][512]
#define WS_UT    ((size_t)20971520)               // U^T bf16 [4096][1024]
#define WS_XZ    ((size_t)29360128)               // xz bf16 [16384][4096]
#define WS_HBUF  ((size_t)163577856)              // hbuf [2][4][8192] dwords
#define WS_FLAGS ((size_t)163840000)              // 256 x u32

#define SCAN_LDS_BYTES 163840                     // 128K Uf + 32K h-stage (zbuf aliased)

__device__ inline unsigned short f2bf(float x) {
    union { float f; uint32_t u; } v; v.f = x;
    uint32_t u = v.u;
    uint32_t r = u + 0x7FFFu + ((u >> 16) & 1u);   // RNE
    return (unsigned short)(r >> 16);
}
__device__ inline unsigned int pack2bf(float a, float b) {
    return (unsigned int)f2bf(a) | ((unsigned int)f2bf(b) << 16);
}
__device__ inline float bf2f(unsigned short h) {
    union { uint32_t u; float f; } v; v.u = ((uint32_t)h) << 16;
    return v.f;
}
__device__ inline float sigmoidf(float z) { return 1.f / (1.f + __expf(-z)); }

// ---------- tiled transpose + cast: out[n*K+k] = bf16(in[k*N+n]) ----------
__global__ void __launch_bounds__(256) transpose_cast_kernel(
    const float* __restrict__ in, unsigned int* __restrict__ out32,
    int K, int N) {
    __shared__ float tile[32][33];
    int k0 = blockIdx.x * 32, n0 = blockIdx.y * 32;
    int lx = threadIdx.x & 31, ly = threadIdx.x >> 5;   // load: lanes along n
#pragma unroll
    for (int r = 0; r < 32; r += 8)
        tile[ly + r][lx] = in[(size_t)(k0 + ly + r) * N + n0 + lx];
    __syncthreads();
    int kp = threadIdx.x & 15, nl = threadIdx.x >> 4;   // store: packed k-pairs
#pragma unroll
    for (int r = 0; r < 32; r += 16) {
        float lo = tile[2 * kp][nl + r], hi = tile[2 * kp + 1][nl + r];
        out32[((size_t)(n0 + nl + r) * K + k0) / 2 + kp] = pack2bf(lo, hi);
    }
}

// ---------- embedding gather + bf16 cast (packed dword writes) ----------
__global__ void __launch_bounds__(256) gather_kernel(
    const int* __restrict__ tokens, const float* __restrict__ emb,
    unsigned int* __restrict__ em32) {
    int r = blockIdx.x;                      // 16384 rows = b*256+t
    int tok = tokens[r];
    const float2* src = (const float2*)(emb + (size_t)tok * NE);
    unsigned int* dst = em32 + (size_t)r * (NE / 2);
    for (int i = threadIdx.x; i < NE / 2; i += 256) {
        float2 v = src[i];
        dst[i] = pack2bf(v.x, v.y);
    }
}

// ---------- GEMM1: xz = em @ W + b   (A[16384][512] bf16, BT[4096][512] bf16) ----------
__global__ void __launch_bounds__(256) gemm1_kernel(
    const unsigned short* __restrict__ A, const unsigned short* __restrict__ BT,
    const float* __restrict__ bias, unsigned short* __restrict__ C) {
    __shared__ unsigned short As[128 * 64];
    __shared__ unsigned short Bs[128 * 64];
    int bid = blockIdx.x;
    int mb = bid & 127, nb = bid >> 7;       // 128 M-tiles x 32 N-tiles
    int tid = threadIdx.x;
    int w = tid >> 6, l = tid & 63;
    int wm = w >> 1, wn = w & 1;             // 64x64 quadrant per wave

    f32x4 acc[4][4];
#pragma unroll
    for (int i = 0; i < 4; i++)
#pragma unroll
        for (int j = 0; j < 4; j++) acc[i][j] = f32x4{0.f, 0.f, 0.f, 0.f};

    for (int kt = 0; kt < 8; ++kt) {         // K=512, BK=64
        short8 av[4], bv[4];
#pragma unroll
        for (int r = 0; r < 4; ++r) {
            int chunk = r * 256 + tid;       // 1024 chunks of 8 bf16
            int row = chunk >> 3, c8 = chunk & 7;
            av[r] = *(const short8*)(A + ((size_t)(mb * 128 + row)) * NE + kt * 64 + c8 * 8);
            bv[r] = *(const short8*)(BT + ((size_t)(nb * 128 + row)) * NE + kt * 64 + c8 * 8);
        }
#pragma unroll
        for (int r = 0; r < 4; ++r) {
            int chunk = r * 256 + tid;
            *(short8*)(As + chunk * 8) = av[r];
            *(short8*)(Bs + chunk * 8) = bv[r];
        }
        __syncthreads();
#pragma unroll
        for (int kk = 0; kk < 2; ++kk) {
            short8 af[4], bf[4];
#pragma unroll
            for (int mi = 0; mi < 4; ++mi)
                af[mi] = *(const short8*)(As + (wm * 64 + mi * 16 + (l & 15)) * 64 + kk * 32 + (l >> 4) * 8);
#pragma unroll
            for (int ni = 0; ni < 4; ++ni)
                bf[ni] = *(const short8*)(Bs + (wn * 64 + ni * 16 + (l & 15)) * 64 + kk * 32 + (l >> 4) * 8);
#pragma unroll
            for (int mi = 0; mi < 4; ++mi)
#pragma unroll
                for (int ni = 0; ni < 4; ++ni)
                    acc[mi][ni] = __builtin_amdgcn_mfma_f32_16x16x32_bf16(af[mi], bf[ni], acc[mi][ni], 0, 0, 0);
        }
        __syncthreads();
    }
    // epilogue: C = bf16(acc + bias)
#pragma unroll
    for (int ni = 0; ni < 4; ++ni) {
        int col = nb * 128 + wn * 64 + ni * 16 + (l & 15);
        float bvv = bias[col];
#pragma unroll
        for (int mi = 0; mi < 4; ++mi) {
#pragma unroll
            for (int r = 0; r < 4; ++r) {
                int row = mb * 128 + wm * 64 + mi * 16 + ((l >> 4) * 4) + r;
                C[(size_t)row * NG + col] = f2bf(acc[mi][ni][r] + bvv);
            }
        }
    }
}

// ---------- persistent LSTM scan ----------
// 256 blocks: p = wg>>6 (batch group of 16), q = wg&63 (16 units x 4 gates).
// U fragments LDS-resident (128 KB). Cross-block h exchange is FENCE-FREE:
// all cross-block traffic uses agent-scope atomics (cache-bypass, coherent at
// L3) -> no buffer_inv/wbl2 per step, L2 keeps XZ cached.
__global__ void __launch_bounds__(256) scan_kernel(
    const unsigned short* __restrict__ UT,   // [4096][1024] bf16 (n-major)
    const unsigned short* __restrict__ XZ,   // [16384][4096] bf16, row = b*256+t
    const float* __restrict__ h0, const float* __restrict__ c0,
    unsigned int* hbuf32,                    // [2][4][8192] dwords (frag layout)
    unsigned int* flags,                     // [256]
    float* __restrict__ out) {
    extern __shared__ unsigned char smem[];
    unsigned short* Uf = (unsigned short*)smem;            // 128 KB
    unsigned short* Hs = (unsigned short*)(smem + 131072); // 32 KB h-stage
    unsigned int* Hs32 = (unsigned int*)(smem + 131072);
    float* zbuf = (float*)(smem + 131072);                 // aliased (behind barrier)

    const int wg = blockIdx.x;
    const int p = wg >> 6, q = wg & 63;
    const int tid = threadIdx.x;
    const int g = tid >> 6;        // wave index == gate
    const int l = tid & 63;

    // ---- stage U fragments into LDS (one-time) ----
    for (int c = tid; c < 8192; c += 256) {
        int ln = c >> 7;                 // 0..63 local col (gate*16 + cl)
        int rem = c & 127;
        int kt = rem >> 2, grp = rem & 3;
        int gate = ln >> 4, cl = ln & 15;
        int ncol = gate * NU + q * 16 + cl;
        short8 v = *(const short8*)(UT + (size_t)ncol * NU + kt * 32 + grp * 8);
        *(short8*)(Uf + (size_t)((gate * 32 + kt) * 64 + grp * 16 + cl) * 8) = v;
    }

    // ---- per-thread ownership for gate combine: (batch-local, unit-local) ----
    const int bl = tid >> 4, ul = tid & 15;
    const int b = p * 16 + bl, u = q * 16 + ul;
    float c_reg = c0[(size_t)b * NU + u];
    {   // publish h0 into parity-0 buffer (packed dwords, write-through)
        float hv = h0[(size_t)b * NU + u];
        unsigned short mybf = f2bf(hv);
        unsigned short obf = (unsigned short)__shfl_xor((int)mybf, 1, 64);
        if ((ul & 1) == 0) {
            int kt = u >> 5, grp = (u >> 3) & 3, j = u & 7;
            int fidx = (kt * 64 + grp * 16 + bl) * 8 + j;
            __hip_atomic_store(&hbuf32[(size_t)p * 8192 + (fidx >> 1)],
                               (unsigned int)mybf | ((unsigned int)obf << 16),
                               __ATOMIC_RELAXED, __HIP_MEMORY_SCOPE_AGENT);
        }
    }
    __syncthreads();                       // vmcnt(0): h0 stores are at L3
    if (tid == 0)
        __hip_atomic_store(&flags[wg], 1u, __ATOMIC_RELEASE, __HIP_MEMORY_SCOPE_AGENT);

    const unsigned short* xz_base = XZ + (size_t)(p * 16) * NT * NG + (size_t)(g * NU + q * 16);
    const int rb0 = (l >> 4) * 4, zc = l & 15;
    float* outO = out;
    float* outH = out + (size_t)NB * NT * NU;
    float* outC = outH + (size_t)NB * NU;

    for (int s = 0; s < NT; ++s) {
        // xz prefetch (plain cached loads) — latency hides under the poll
        float xv[4];
#pragma unroll
        for (int r = 0; r < 4; ++r)
            xv[r] = bf2f(xz_base[(size_t)((rb0 + r) * NT + s) * NG + zc]);

        // wait for all 64 producers of my batch group (relaxed, no fence)
        if (tid < 64) {
            const unsigned int target = (unsigned int)(s + 1);
            unsigned int* fl = &flags[p * 64 + tid];
            while (__hip_atomic_load(fl, __ATOMIC_RELAXED, __HIP_MEMORY_SCOPE_AGENT) < target)
                __builtin_amdgcn_s_sleep(1);
        }
        __syncthreads();

        // cooperative h-stage: 8192 dwords from L3 -> LDS (once per block)
        const unsigned int* hb = hbuf32 + (size_t)((s & 1) * 4 + p) * 8192;
        unsigned int tmp[32];
#pragma unroll
        for (int i = 0; i < 32; ++i)
            tmp[i] = __hip_atomic_load(hb + i * 256 + tid, __ATOMIC_RELAXED, __HIP_MEMORY_SCOPE_AGENT);
#pragma unroll
        for (int i = 0; i < 32; ++i)
            Hs32[i * 256 + tid] = tmp[i];
        __syncthreads();

        f32x4 acc = f32x4{0.f, 0.f, 0.f, 0.f};
#pragma unroll
        for (int kt = 0; kt < 32; ++kt) {
            short8 af = *(const short8*)(Hs + (kt * 64 + l) * 8);
            short8 bfg = *(const short8*)(Uf + ((g * 32 + kt) * 64 + l) * 8);
            acc = __builtin_amdgcn_mfma_f32_16x16x32_bf16(af, bfg, acc, 0, 0, 0);
        }
        __syncthreads();                   // Hs reads done before zbuf alias writes

        {   // z = acc + xz  -> zbuf[gate][batch][unit]
#pragma unroll
            for (int r = 0; r < 4; ++r)
                zbuf[(g * 16 + rb0 + r) * 17 + zc] = acc[r] + xv[r];
        }
        __syncthreads();
        {   // gate combine (thread owns (bl, ul))
            float zi = zbuf[(0 * 16 + bl) * 17 + ul];
            float zf = zbuf[(1 * 16 + bl) * 17 + ul];
            float zg = zbuf[(2 * 16 + bl) * 17 + ul];
            float zo = zbuf[(3 * 16 + bl) * 17 + ul];
            float gi = sigmoidf(zi), gf = sigmoidf(zf);
            float gg = sigmoidf(zg), go = sigmoidf(zo);
            c_reg = gf * c_reg + gi * gg;
            float h = go * sigmoidf(c_reg);
            __hip_atomic_store(&outO[((size_t)b * NT + s) * NU + u], h,
                               __ATOMIC_RELAXED, __HIP_MEMORY_SCOPE_AGENT);
            unsigned short mybf = f2bf(h);
            unsigned short obf = (unsigned short)__shfl_xor((int)mybf, 1, 64);
            if ((ul & 1) == 0) {
                int kt = u >> 5, grp = (u >> 3) & 3, j = u & 7;
                int fidx = (kt * 64 + grp * 16 + bl) * 8 + j;
                __hip_atomic_store(&hbuf32[(size_t)(((s + 1) & 1) * 4 + p) * 8192 + (fidx >> 1)],
                                   (unsigned int)mybf | ((unsigned int)obf << 16),
                                   __ATOMIC_RELAXED, __HIP_MEMORY_SCOPE_AGENT);
            }
            if (s == NT - 1) {
                __hip_atomic_store(&outH[(size_t)b * NU + u], h,
                                   __ATOMIC_RELAXED, __HIP_MEMORY_SCOPE_AGENT);
                __hip_atomic_store(&outC[(size_t)b * NU + u], c_reg,
                                   __ATOMIC_RELAXED, __HIP_MEMORY_SCOPE_AGENT);
            }
        }
        __syncthreads();                   // vmcnt(0): h stores at L3, zbuf reads done
        if (tid == 0)
            __hip_atomic_store(&flags[wg], (unsigned int)(s + 2), __ATOMIC_RELEASE, __HIP_MEMORY_SCOPE_AGENT);
    }
}

extern "C" void kernel_launch(void* const* d_in, const int* in_sizes, int n_in,
                              void* d_out, int out_size, void* d_ws, size_t ws_size,
                              hipStream_t stream) {
    const int* tokens = (const int*)d_in[0];
    const float* h0 = (const float*)d_in[1];
    const float* c0 = (const float*)d_in[2];
    const float* emb = (const float*)d_in[3];
    const float* W = (const float*)d_in[4];
    const float* U = (const float*)d_in[5];
    const float* bias = (const float*)d_in[6];
    float* out = (float*)d_out;

    unsigned char* ws = (unsigned char*)d_ws;
    unsigned short* em_bf = (unsigned short*)(ws + WS_EM);
    unsigned short* WT = (unsigned short*)(ws + WS_WT);
    unsigned short* UT = (unsigned short*)(ws + WS_UT);
    unsigned short* XZ = (unsigned short*)(ws + WS_XZ);
    unsigned int* hbuf32 = (unsigned int*)(ws + WS_HBUF);
    unsigned int* flags = (unsigned int*)(ws + WS_FLAGS);

    hipMemsetAsync(flags, 0, 1024, stream);

    // W [512][4096] -> WT [4096][512] bf16
    transpose_cast_kernel<<<dim3(NE / 32, NG / 32), 256, 0, stream>>>(W, (unsigned int*)WT, NE, NG);
    // U [1024][4096] -> UT [4096][1024] bf16
    transpose_cast_kernel<<<dim3(NU / 32, NG / 32), 256, 0, stream>>>(U, (unsigned int*)UT, NU, NG);
    gather_kernel<<<ROWS, 256, 0, stream>>>(tokens, emb, (unsigned int*)em_bf);
    gemm1_kernel<<<4096, 256, 0, stream>>>(em_bf, WT, bias, XZ);

    hipFuncSetAttribute((const void*)scan_kernel,
                        hipFuncAttributeMaxDynamicSharedMemorySize, SCAN_LDS_BYTES);
    scan_kernel<<<256, 256, SCAN_LDS_BYTES, stream>>>(UT, XZ, h0, c0, hbuf32, flags, out);
}

// Round 3
// 1358.220 us; speedup vs baseline: 5.0098x; 1.7318x over previous
//
#include <hip/hip_runtime.h>
#include <stdint.h>

// Encoder: embedding gather + xz GEMM + sequential LSTM (all-sigmoid) scan.
// B=64, T=256, E=512, UNITS=1024, gates 4*1024, gate order [i,f,g,o].

typedef __attribute__((ext_vector_type(8))) short short8;
typedef __attribute__((ext_vector_type(4))) float f32x4;
typedef __attribute__((ext_vector_type(4))) unsigned int u32x4;

#define NB 64
#define NT 256
#define NE 512
#define NU 1024
#define NG 4096
#define ROWS (NB*NT)          // 16384

// workspace layout (bytes)
#define WS_EM    ((size_t)0)                      // em_bf16 [16384][512]
#define WS_WT    ((size_t)16777216)               // W^T bf16 [4096][512]
#define WS_UT    ((size_t)20971520)               // U^T bf16 [4096][1024]
#define WS_XZ    ((size_t)29360128)               // xz bf16 [16384][4096]
#define WS_HBUF  ((size_t)163577856)              // hbuf [2][4][8192] dwords
#define WS_FLAGS ((size_t)163840000)              // 256 x u32

// LDS actually used: 32KB Hs + 4.25KB zbuf. Allocate 128KB to pin 1 block/CU.
#define SCAN_LDS_BYTES 131072

__device__ inline unsigned short f2bf(float x) {
    union { float f; uint32_t u; } v; v.f = x;
    uint32_t u = v.u;
    uint32_t r = u + 0x7FFFu + ((u >> 16) & 1u);   // RNE
    return (unsigned short)(r >> 16);
}
__device__ inline unsigned int pack2bf(float a, float b) {
    return (unsigned int)f2bf(a) | ((unsigned int)f2bf(b) << 16);
}
__device__ inline float bf2f(unsigned short h) {
    union { uint32_t u; float f; } v; v.u = ((uint32_t)h) << 16;
    return v.f;
}
__device__ inline float sigmoidf(float z) { return 1.f / (1.f + __expf(-z)); }

// ---- coherent (L3, cache-bypass) access helpers: sc0 sc1 flagged ops ----
__device__ inline void store_dword_sc(unsigned int* addr, unsigned int v) {
    asm volatile("global_store_dword %0, %1, off sc0 sc1" :: "v"(addr), "v"(v) : "memory");
}
__device__ inline u32x4 load_b128_sc(const unsigned int* addr) {
    u32x4 r;
    asm volatile("global_load_dwordx4 %0, %1, off sc0 sc1" : "=v"(r) : "v"(addr) : "memory");
    return r;
}
__device__ inline unsigned int load_dword_sc_wait(const unsigned int* addr) {
    unsigned int r;
    asm volatile("global_load_dword %0, %1, off sc0 sc1\n\ts_waitcnt vmcnt(0)"
                 : "=v"(r) : "v"(addr) : "memory");
    return r;
}
__device__ inline void wait_vm0() {
    asm volatile("s_waitcnt vmcnt(0)" ::: "memory");
}

// ---------- tiled transpose + cast: out[n*K+k] = bf16(in[k*N+n]) ----------
__global__ void __launch_bounds__(256) transpose_cast_kernel(
    const float* __restrict__ in, unsigned int* __restrict__ out32,
    int K, int N) {
    __shared__ float tile[32][33];
    int k0 = blockIdx.x * 32, n0 = blockIdx.y * 32;
    int lx = threadIdx.x & 31, ly = threadIdx.x >> 5;   // load: lanes along n
#pragma unroll
    for (int r = 0; r < 32; r += 8)
        tile[ly + r][lx] = in[(size_t)(k0 + ly + r) * N + n0 + lx];
    __syncthreads();
    int kp = threadIdx.x & 15, nl = threadIdx.x >> 4;   // store: packed k-pairs
#pragma unroll
    for (int r = 0; r < 32; r += 16) {
        float lo = tile[2 * kp][nl + r], hi = tile[2 * kp + 1][nl + r];
        out32[((size_t)(n0 + nl + r) * K + k0) / 2 + kp] = pack2bf(lo, hi);
    }
}

// ---------- embedding gather + bf16 cast (packed dword writes) ----------
__global__ void __launch_bounds__(256) gather_kernel(
    const int* __restrict__ tokens, const float* __restrict__ emb,
    unsigned int* __restrict__ em32) {
    int r = blockIdx.x;                      // 16384 rows = b*256+t
    int tok = tokens[r];
    const float2* src = (const float2*)(emb + (size_t)tok * NE);
    unsigned int* dst = em32 + (size_t)r * (NE / 2);
    for (int i = threadIdx.x; i < NE / 2; i += 256) {
        float2 v = src[i];
        dst[i] = pack2bf(v.x, v.y);
    }
}

// ---------- GEMM1: xz = em @ W + b   (A[16384][512] bf16, BT[4096][512] bf16) ----------
__global__ void __launch_bounds__(256) gemm1_kernel(
    const unsigned short* __restrict__ A, const unsigned short* __restrict__ BT,
    const float* __restrict__ bias, unsigned short* __restrict__ C) {
    __shared__ unsigned short As[128 * 64];
    __shared__ unsigned short Bs[128 * 64];
    int bid = blockIdx.x;
    int mb = bid & 127, nb = bid >> 7;       // 128 M-tiles x 32 N-tiles
    int tid = threadIdx.x;
    int w = tid >> 6, l = tid & 63;
    int wm = w >> 1, wn = w & 1;             // 64x64 quadrant per wave

    f32x4 acc[4][4];
#pragma unroll
    for (int i = 0; i < 4; i++)
#pragma unroll
        for (int j = 0; j < 4; j++) acc[i][j] = f32x4{0.f, 0.f, 0.f, 0.f};

    for (int kt = 0; kt < 8; ++kt) {         // K=512, BK=64
        short8 av[4], bv[4];
#pragma unroll
        for (int r = 0; r < 4; ++r) {
            int chunk = r * 256 + tid;       // 1024 chunks of 8 bf16
            int row = chunk >> 3, c8 = chunk & 7;
            av[r] = *(const short8*)(A + ((size_t)(mb * 128 + row)) * NE + kt * 64 + c8 * 8);
            bv[r] = *(const short8*)(BT + ((size_t)(nb * 128 + row)) * NE + kt * 64 + c8 * 8);
        }
#pragma unroll
        for (int r = 0; r < 4; ++r) {
            int chunk = r * 256 + tid;
            *(short8*)(As + chunk * 8) = av[r];
            *(short8*)(Bs + chunk * 8) = bv[r];
        }
        __syncthreads();
#pragma unroll
        for (int kk = 0; kk < 2; ++kk) {
            short8 af[4], bf[4];
#pragma unroll
            for (int mi = 0; mi < 4; ++mi)
                af[mi] = *(const short8*)(As + (wm * 64 + mi * 16 + (l & 15)) * 64 + kk * 32 + (l >> 4) * 8);
#pragma unroll
            for (int ni = 0; ni < 4; ++ni)
                bf[ni] = *(const short8*)(Bs + (wn * 64 + ni * 16 + (l & 15)) * 64 + kk * 32 + (l >> 4) * 8);
#pragma unroll
            for (int mi = 0; mi < 4; ++mi)
#pragma unroll
                for (int ni = 0; ni < 4; ++ni)
                    acc[mi][ni] = __builtin_amdgcn_mfma_f32_16x16x32_bf16(af[mi], bf[ni], acc[mi][ni], 0, 0, 0);
        }
        __syncthreads();
    }
    // epilogue: C = bf16(acc + bias)
#pragma unroll
    for (int ni = 0; ni < 4; ++ni) {
        int col = nb * 128 + wn * 64 + ni * 16 + (l & 15);
        float bvv = bias[col];
#pragma unroll
        for (int mi = 0; mi < 4; ++mi) {
#pragma unroll
            for (int r = 0; r < 4; ++r) {
                int row = mb * 128 + wm * 64 + mi * 16 + ((l >> 4) * 4) + r;
                C[(size_t)row * NG + col] = f2bf(acc[mi][ni][r] + bvv);
            }
        }
    }
}

// ---------- persistent LSTM scan ----------
// 256 blocks: p = wg>>6 (batch group of 16), q = wg&63 (16 units x 4 gates).
// U fragments REGISTER-resident (128 VGPR/lane). Cross-block h exchange is
// fence-free via sc0|sc1 (L3-coherent, cache-bypass) inline-asm ops, batched
// with a single vmcnt(0) drain per phase.
__global__ void __launch_bounds__(256, 1) scan_kernel(
    const unsigned short* __restrict__ UT,   // [4096][1024] bf16 (n-major)
    const unsigned short* __restrict__ XZ,   // [16384][4096] bf16, row = b*256+t
    const float* __restrict__ h0, const float* __restrict__ c0,
    unsigned int* hbuf32,                    // [2][4][8192] dwords (frag layout)
    unsigned int* flags,                     // [256]
    float* __restrict__ out) {
    extern __shared__ unsigned char smem[];
    unsigned short* Hs = (unsigned short*)smem;            // 32 KB h-stage
    unsigned int* Hs32 = (unsigned int*)smem;
    float* zbuf = (float*)(smem + 32768);                  // [4][16][17] f32

    const int wg = blockIdx.x;
    const int p = wg >> 6, q = wg & 63;
    const int tid = threadIdx.x;
    const int g = tid >> 6;        // wave index == gate
    const int l = tid & 63;

    // ---- U fragments -> registers (one-time; 32 x short8 = 128 VGPR) ----
    // lane l, kt: UT[g*1024 + q*16 + (l&15)][kt*32 + (l>>4)*8 .. +8]
    short8 Ufrag[32];
    {
        const unsigned short* urow =
            UT + ((size_t)(g * NU + q * 16 + (l & 15))) * NU + (l >> 4) * 8;
#pragma unroll
        for (int kt = 0; kt < 32; ++kt)
            Ufrag[kt] = *(const short8*)(urow + kt * 32);
    }

    // ---- per-thread ownership for gate combine: (batch-local, unit-local) ----
    const int bl = tid >> 4, ul = tid & 15;
    const int b = p * 16 + bl, u = q * 16 + ul;
    float c_reg = c0[(size_t)b * NU + u];
    {   // publish h0 into parity-0 buffer (packed dwords, coherent stores)
        float hv = h0[(size_t)b * NU + u];
        unsigned short mybf = f2bf(hv);
        unsigned short obf = (unsigned short)__shfl_xor((int)mybf, 1, 64);
        if ((ul & 1) == 0) {
            int kt = u >> 5, grp = (u >> 3) & 3, j = u & 7;
            int fidx = (kt * 64 + grp * 16 + bl) * 8 + j;
            store_dword_sc(&hbuf32[(size_t)p * 8192 + (fidx >> 1)],
                           (unsigned int)mybf | ((unsigned int)obf << 16));
        }
    }
    wait_vm0();
    __syncthreads();
    if (tid == 0) store_dword_sc(&flags[wg], 1u);

    const unsigned short* xz_base = XZ + (size_t)(p * 16) * NT * NG + (size_t)(g * NU + q * 16);
    const int rb0 = (l >> 4) * 4, zc = l & 15;
    float* outO = out;
    float* outH = out + (size_t)NB * NT * NU;
    float* outC = outH + (size_t)NB * NU;

    for (int s = 0; s < NT; ++s) {
        // xz prefetch (plain cached loads) — latency hides under the poll
        float xv[4];
#pragma unroll
        for (int r = 0; r < 4; ++r)
            xv[r] = bf2f(xz_base[(size_t)((rb0 + r) * NT + s) * NG + zc]);

        // wait for all 64 producers of my batch group
        if (tid < 64) {
            const unsigned int target = (unsigned int)(s + 1);
            const unsigned int* fl = &flags[p * 64 + tid];
            while (load_dword_sc_wait(fl) < target) { /* spin */ }
        }
        __syncthreads();

        // cooperative h-stage: 8192 dwords (32 KB) L3 -> LDS, batched 16B loads
        {
            const unsigned int* hb = hbuf32 + (size_t)((s & 1) * 4 + p) * 8192;
            u32x4 t[8];
#pragma unroll
            for (int k = 0; k < 8; ++k)
                t[k] = load_b128_sc(hb + k * 1024 + tid * 4);
            wait_vm0();
            __builtin_amdgcn_sched_barrier(0);
#pragma unroll
            for (int k = 0; k < 8; ++k)
                *(u32x4*)(Hs32 + k * 1024 + tid * 4) = t[k];
        }
        __syncthreads();

        // z(g-slice) = Hs @ Ufrag : 32 MFMA, 4 independent acc chains
        f32x4 ac0 = f32x4{0.f, 0.f, 0.f, 0.f}, ac1 = ac0, ac2 = ac0, ac3 = ac0;
#pragma unroll
        for (int kt = 0; kt < 32; kt += 4) {
            short8 a0 = *(const short8*)(Hs + ((kt + 0) * 64 + l) * 8);
            short8 a1 = *(const short8*)(Hs + ((kt + 1) * 64 + l) * 8);
            short8 a2 = *(const short8*)(Hs + ((kt + 2) * 64 + l) * 8);
            short8 a3 = *(const short8*)(Hs + ((kt + 3) * 64 + l) * 8);
            ac0 = __builtin_amdgcn_mfma_f32_16x16x32_bf16(a0, Ufrag[kt + 0], ac0, 0, 0, 0);
            ac1 = __builtin_amdgcn_mfma_f32_16x16x32_bf16(a1, Ufrag[kt + 1], ac1, 0, 0, 0);
            ac2 = __builtin_amdgcn_mfma_f32_16x16x32_bf16(a2, Ufrag[kt + 2], ac2, 0, 0, 0);
            ac3 = __builtin_amdgcn_mfma_f32_16x16x32_bf16(a3, Ufrag[kt + 3], ac3, 0, 0, 0);
        }
        f32x4 acc = (ac0 + ac1) + (ac2 + ac3);

        {   // z = acc + xz  -> zbuf[gate][batch][unit]
#pragma unroll
            for (int r = 0; r < 4; ++r)
                zbuf[(g * 16 + rb0 + r) * 17 + zc] = acc[r] + xv[r];
        }
        __syncthreads();
        {   // gate combine (thread owns (bl, ul))
            float zi = zbuf[(0 * 16 + bl) * 17 + ul];
            float zf = zbuf[(1 * 16 + bl) * 17 + ul];
            float zg = zbuf[(2 * 16 + bl) * 17 + ul];
            float zo = zbuf[(3 * 16 + bl) * 17 + ul];
            float gi = sigmoidf(zi), gf = sigmoidf(zf);
            float gg = sigmoidf(zg), go = sigmoidf(zo);
            c_reg = gf * c_reg + gi * gg;
            float h = go * sigmoidf(c_reg);
            outO[((size_t)b * NT + s) * NU + u] = h;          // plain store (L2)
            unsigned short mybf = f2bf(h);
            unsigned short obf = (unsigned short)__shfl_xor((int)mybf, 1, 64);
            if ((ul & 1) == 0) {
                int kt = u >> 5, grp = (u >> 3) & 3, j = u & 7;
                int fidx = (kt * 64 + grp * 16 + bl) * 8 + j;
                store_dword_sc(&hbuf32[(size_t)(((s + 1) & 1) * 4 + p) * 8192 + (fidx >> 1)],
                               (unsigned int)mybf | ((unsigned int)obf << 16));
            }
            if (s == NT - 1) {
                outH[(size_t)b * NU + u] = h;
                outC[(size_t)b * NU + u] = c_reg;
            }
        }
        wait_vm0();                        // h stores ack'd at L3
        __syncthreads();                   // all threads' h stores drained
        if (tid == 0)
            store_dword_sc(&flags[wg], (unsigned int)(s + 2));
    }
}

extern "C" void kernel_launch(void* const* d_in, const int* in_sizes, int n_in,
                              void* d_out, int out_size, void* d_ws, size_t ws_size,
                              hipStream_t stream) {
    const int* tokens = (const int*)d_in[0];
    const float* h0 = (const float*)d_in[1];
    const float* c0 = (const float*)d_in[2];
    const float* emb = (const float*)d_in[3];
    const float* W = (const float*)d_in[4];
    const float* U = (const float*)d_in[5];
    const float* bias = (const float*)d_in[6];
    float* out = (float*)d_out;

    unsigned char* ws = (unsigned char*)d_ws;
    unsigned short* em_bf = (unsigned short*)(ws + WS_EM);
    unsigned short* WT = (unsigned short*)(ws + WS_WT);
    unsigned short* UT = (unsigned short*)(ws + WS_UT);
    unsigned short* XZ = (unsigned short*)(ws + WS_XZ);
    unsigned int* hbuf32 = (unsigned int*)(ws + WS_HBUF);
    unsigned int* flags = (unsigned int*)(ws + WS_FLAGS);

    hipMemsetAsync(flags, 0, 1024, stream);

    // W [512][4096] -> WT [4096][512] bf16
    transpose_cast_kernel<<<dim3(NE / 32, NG / 32), 256, 0, stream>>>(W, (unsigned int*)WT, NE, NG);
    // U [1024][4096] -> UT [4096][1024] bf16
    transpose_cast_kernel<<<dim3(NU / 32, NG / 32), 256, 0, stream>>>(U, (unsigned int*)UT, NU, NG);
    gather_kernel<<<ROWS, 256, 0, stream>>>(tokens, emb, (unsigned int*)em_bf);
    gemm1_kernel<<<4096, 256, 0, stream>>>(em_bf, WT, bias, XZ);

    hipFuncSetAttribute((const void*)scan_kernel,
                        hipFuncAttributeMaxDynamicSharedMemorySize, SCAN_LDS_BYTES);
    scan_kernel<<<256, 256, SCAN_LDS_BYTES, stream>>>(UT, XZ, h0, c0, hbuf32, flags, out);
}

// Round 4
// 1142.094 us; speedup vs baseline: 5.9579x; 1.1892x over previous
//
#include <hip/hip_runtime.h>
#include <stdint.h>

// Encoder: embedding gather + xz GEMM + sequential LSTM (all-sigmoid) scan.
// B=64, T=256, E=512, UNITS=1024, gates 4*1024, gate order [i,f,g,o].

typedef __attribute__((ext_vector_type(8))) short short8;
typedef __attribute__((ext_vector_type(4))) float f32x4;
typedef __attribute__((ext_vector_type(4))) unsigned int u32x4;

#define NB 64
#define NT 256
#define NE 512
#define NU 1024
#define NG 4096
#define ROWS (NB*NT)          // 16384

// workspace layout (bytes)
#define WS_EM    ((size_t)0)                      // em_bf16 [16384][512]
#define WS_WT    ((size_t)16777216)               // W^T bf16 [4096][512]
#define WS_UT    ((size_t)20971520)               // U^T bf16 [4096][1024]
#define WS_XZ    ((size_t)29360128)               // xz bf16 [16384][4096]
#define WS_HBUF  ((size_t)163577856)              // legacy hbuf [2][4][8192] dwords
#define WS_FLAGS ((size_t)163840000)              // legacy 256 x u32
#define WS_RING  ((size_t)163841024)              // hring [257][4][8192] dwords (if ws fits)
#define RING_DWORDS ((size_t)257 * 4 * 8192)      // 8,421,376
#define RING_BYTES  (RING_DWORDS * 4)             // 33,685,504

#define SENT 0x7FC07FC0u   // NaN|NaN packed bf16 — impossible for finite h pairs

// LDS actually used: 32KB Hs + 4.25KB zbuf. Allocate 128KB to pin 1 block/CU
// (grid=256 => all blocks co-resident; required for the persistent scan).
#define SCAN_LDS_BYTES 131072

__device__ inline unsigned short f2bf(float x) {
    union { float f; uint32_t u; } v; v.f = x;
    uint32_t u = v.u;
    uint32_t r = u + 0x7FFFu + ((u >> 16) & 1u);   // RNE
    return (unsigned short)(r >> 16);
}
__device__ inline unsigned int pack2bf(float a, float b) {
    return (unsigned int)f2bf(a) | ((unsigned int)f2bf(b) << 16);
}
__device__ inline float bf2f(unsigned short h) {
    union { uint32_t u; float f; } v; v.u = ((uint32_t)h) << 16;
    return v.f;
}
__device__ inline float sigmoidf(float z) { return 1.f / (1.f + __expf(-z)); }

// ---- coherent (L3, cache-bypass) access helpers: sc0 sc1 flagged ops ----
__device__ inline void store_dword_sc(unsigned int* addr, unsigned int v) {
    asm volatile("global_store_dword %0, %1, off sc0 sc1" :: "v"(addr), "v"(v) : "memory");
}
__device__ inline void store_b128_sc(unsigned int* addr, u32x4 v) {
    asm volatile("global_store_dwordx4 %0, %1, off sc0 sc1" :: "v"(addr), "v"(v) : "memory");
}
__device__ inline u32x4 load_b128_sc(const unsigned int* addr) {
    u32x4 r;
    asm volatile("global_load_dwordx4 %0, %1, off sc0 sc1" : "=v"(r) : "v"(addr) : "memory");
    return r;
}
__device__ inline unsigned int load_dword_sc_wait(const unsigned int* addr) {
    unsigned int r;
    asm volatile("global_load_dword %0, %1, off sc0 sc1\n\ts_waitcnt vmcnt(0)"
                 : "=v"(r) : "v"(addr) : "memory");
    return r;
}
__device__ inline void wait_vm0() {
    asm volatile("s_waitcnt vmcnt(0)" ::: "memory");
}

// ---------- sentinel fill for the h ring ----------
__global__ void __launch_bounds__(256) fill_ring_kernel(unsigned int* p, size_t nvec4) {
    u32x4 s4 = u32x4{SENT, SENT, SENT, SENT};
    size_t stride = (size_t)gridDim.x * 256;
    for (size_t i = blockIdx.x * 256 + threadIdx.x; i < nvec4; i += stride)
        store_b128_sc(p + i * 4, s4);
}

// ---------- tiled transpose + cast: out[n*K+k] = bf16(in[k*N+n]) ----------
__global__ void __launch_bounds__(256) transpose_cast_kernel(
    const float* __restrict__ in, unsigned int* __restrict__ out32,
    int K, int N) {
    __shared__ float tile[32][33];
    int k0 = blockIdx.x * 32, n0 = blockIdx.y * 32;
    int lx = threadIdx.x & 31, ly = threadIdx.x >> 5;   // load: lanes along n
#pragma unroll
    for (int r = 0; r < 32; r += 8)
        tile[ly + r][lx] = in[(size_t)(k0 + ly + r) * N + n0 + lx];
    __syncthreads();
    int kp = threadIdx.x & 15, nl = threadIdx.x >> 4;   // store: packed k-pairs
#pragma unroll
    for (int r = 0; r < 32; r += 16) {
        float lo = tile[2 * kp][nl + r], hi = tile[2 * kp + 1][nl + r];
        out32[((size_t)(n0 + nl + r) * K + k0) / 2 + kp] = pack2bf(lo, hi);
    }
}

// ---------- embedding gather + bf16 cast (packed dword writes) ----------
__global__ void __launch_bounds__(256) gather_kernel(
    const int* __restrict__ tokens, const float* __restrict__ emb,
    unsigned int* __restrict__ em32) {
    int r = blockIdx.x;                      // 16384 rows = b*256+t
    int tok = tokens[r];
    const float2* src = (const float2*)(emb + (size_t)tok * NE);
    unsigned int* dst = em32 + (size_t)r * (NE / 2);
    for (int i = threadIdx.x; i < NE / 2; i += 256) {
        float2 v = src[i];
        dst[i] = pack2bf(v.x, v.y);
    }
}

// ---------- GEMM1: xz = em @ W + b   (A[16384][512] bf16, BT[4096][512] bf16) ----------
__global__ void __launch_bounds__(256) gemm1_kernel(
    const unsigned short* __restrict__ A, const unsigned short* __restrict__ BT,
    const float* __restrict__ bias, unsigned short* __restrict__ C) {
    __shared__ unsigned short As[128 * 64];
    __shared__ unsigned short Bs[128 * 64];
    int bid = blockIdx.x;
    int mb = bid & 127, nb = bid >> 7;       // 128 M-tiles x 32 N-tiles
    int tid = threadIdx.x;
    int w = tid >> 6, l = tid & 63;
    int wm = w >> 1, wn = w & 1;             // 64x64 quadrant per wave

    f32x4 acc[4][4];
#pragma unroll
    for (int i = 0; i < 4; i++)
#pragma unroll
        for (int j = 0; j < 4; j++) acc[i][j] = f32x4{0.f, 0.f, 0.f, 0.f};

    for (int kt = 0; kt < 8; ++kt) {         // K=512, BK=64
        short8 av[4], bv[4];
#pragma unroll
        for (int r = 0; r < 4; ++r) {
            int chunk = r * 256 + tid;       // 1024 chunks of 8 bf16
            int row = chunk >> 3, c8 = chunk & 7;
            av[r] = *(const short8*)(A + ((size_t)(mb * 128 + row)) * NE + kt * 64 + c8 * 8);
            bv[r] = *(const short8*)(BT + ((size_t)(nb * 128 + row)) * NE + kt * 64 + c8 * 8);
        }
#pragma unroll
        for (int r = 0; r < 4; ++r) {
            int chunk = r * 256 + tid;
            *(short8*)(As + chunk * 8) = av[r];
            *(short8*)(Bs + chunk * 8) = bv[r];
        }
        __syncthreads();
#pragma unroll
        for (int kk = 0; kk < 2; ++kk) {
            short8 af[4], bf[4];
#pragma unroll
            for (int mi = 0; mi < 4; ++mi)
                af[mi] = *(const short8*)(As + (wm * 64 + mi * 16 + (l & 15)) * 64 + kk * 32 + (l >> 4) * 8);
#pragma unroll
            for (int ni = 0; ni < 4; ++ni)
                bf[ni] = *(const short8*)(Bs + (wn * 64 + ni * 16 + (l & 15)) * 64 + kk * 32 + (l >> 4) * 8);
#pragma unroll
            for (int mi = 0; mi < 4; ++mi)
#pragma unroll
                for (int ni = 0; ni < 4; ++ni)
                    acc[mi][ni] = __builtin_amdgcn_mfma_f32_16x16x32_bf16(af[mi], bf[ni], acc[mi][ni], 0, 0, 0);
        }
        __syncthreads();
    }
    // epilogue: C = bf16(acc + bias)
#pragma unroll
    for (int ni = 0; ni < 4; ++ni) {
        int col = nb * 128 + wn * 64 + ni * 16 + (l & 15);
        float bvv = bias[col];
#pragma unroll
        for (int mi = 0; mi < 4; ++mi) {
#pragma unroll
            for (int r = 0; r < 4; ++r) {
                int row = mb * 128 + wm * 64 + mi * 16 + ((l >> 4) * 4) + r;
                C[(size_t)row * NG + col] = f2bf(acc[mi][ni][r] + bvv);
            }
        }
    }
}

// ---------- persistent LSTM scan, RING version (flagless sentinel protocol) ----------
// 256 blocks: p = wg>>6 (batch group of 16), q = wg&63 (16 units x 4 gates).
// U fragments register-resident. Each step s has a dedicated ring slot:
// consumers retry-load slot[s] until no sentinel dwords remain; producers
// fire-and-forget sc stores into slot[s+1]. No flags, no drains, no
// inter-block barriers; blocks may skew by <=1 step; no slot reuse => no ABA.
__global__ void __launch_bounds__(256, 1) scan_ring_kernel(
    const unsigned short* __restrict__ UT,   // [4096][1024] bf16 (n-major)
    const unsigned short* __restrict__ XZ,   // [16384][4096] bf16, row = b*256+t
    const float* __restrict__ h0, const float* __restrict__ c0,
    unsigned int* hring,                     // [257][4][8192] dwords (frag layout)
    float* __restrict__ out) {
    extern __shared__ unsigned char smem[];
    unsigned short* Hs = (unsigned short*)smem;            // 32 KB h-stage
    unsigned int* Hs32 = (unsigned int*)smem;
    float* zbuf = (float*)(smem + 32768);                  // [4][16][17] f32

    const int wg = blockIdx.x;
    const int p = wg >> 6, q = wg & 63;
    const int tid = threadIdx.x;
    const int g = tid >> 6;        // wave index == gate
    const int l = tid & 63;

    // ---- U fragments -> registers (one-time; 32 x short8) ----
    short8 Ufrag[32];
    {
        const unsigned short* urow =
            UT + ((size_t)(g * NU + q * 16 + (l & 15))) * NU + (l >> 4) * 8;
#pragma unroll
        for (int kt = 0; kt < 32; ++kt)
            Ufrag[kt] = *(const short8*)(urow + kt * 32);
    }

    // ---- per-thread ownership for gate combine: (batch-local, unit-local) ----
    const int bl = tid >> 4, ul = tid & 15;
    const int b = p * 16 + bl, u = q * 16 + ul;
    float c_reg = c0[(size_t)b * NU + u];
    {   // publish h0 into slot 0 (fire-and-forget; consumers sentinel-poll)
        float hv = h0[(size_t)b * NU + u];
        unsigned short mybf = f2bf(hv);
        unsigned short obf = (unsigned short)__shfl_xor((int)mybf, 1, 64);
        if ((ul & 1) == 0) {
            int kt = u >> 5, grp = (u >> 3) & 3, j = u & 7;
            int fidx = (kt * 64 + grp * 16 + bl) * 8 + j;
            store_dword_sc(&hring[(size_t)p * 8192 + (fidx >> 1)],
                           (unsigned int)mybf | ((unsigned int)obf << 16));
        }
    }

    const unsigned short* xz_base = XZ + (size_t)(p * 16) * NT * NG + (size_t)(g * NU + q * 16);
    const int rb0 = (l >> 4) * 4, zc = l & 15;
    float* outO = out;
    float* outH = out + (size_t)NB * NT * NU;
    float* outC = outH + (size_t)NB * NU;

    for (int s = 0; s < NT; ++s) {
        // xz prefetch (plain cached loads) — overlaps the retry window
        float xv[4];
#pragma unroll
        for (int r = 0; r < 4; ++r)
            xv[r] = bf2f(xz_base[(size_t)((rb0 + r) * NT + s) * NG + zc]);

        // consume slot[s]: retry-load until sentinel-free (per-vector retries)
        const unsigned int* hb = hring + ((size_t)s * 4 + p) * 8192;
        u32x4 t[8];
#pragma unroll
        for (int k = 0; k < 8; ++k)
            t[k] = load_b128_sc(hb + k * 1024 + tid * 4);
        wait_vm0();
        for (;;) {
            unsigned int badmask = 0;
#pragma unroll
            for (int k = 0; k < 8; ++k) {
                u32x4 v = t[k];
                if (v.x == SENT || v.y == SENT || v.z == SENT || v.w == SENT)
                    badmask |= 1u << k;
            }
            if (!__any((int)(badmask != 0))) break;
#pragma unroll
            for (int k = 0; k < 8; ++k)
                if (badmask & (1u << k))
                    t[k] = load_b128_sc(hb + k * 1024 + tid * 4);
            wait_vm0();
        }
        __builtin_amdgcn_sched_barrier(0);
        // Safe to overwrite Hs: all waves passed the previous step's
        // post-zbuf barrier, so no wave is still reading Hs.
#pragma unroll
        for (int k = 0; k < 8; ++k)
            *(u32x4*)(Hs32 + k * 1024 + tid * 4) = t[k];
        __syncthreads();                     // barrier 1

        // z(g-slice) = Hs @ Ufrag : 32 MFMA, 4 independent acc chains
        f32x4 ac0 = f32x4{0.f, 0.f, 0.f, 0.f}, ac1 = ac0, ac2 = ac0, ac3 = ac0;
#pragma unroll
        for (int kt = 0; kt < 32; kt += 4) {
            short8 a0 = *(const short8*)(Hs + ((kt + 0) * 64 + l) * 8);
            short8 a1 = *(const short8*)(Hs + ((kt + 1) * 64 + l) * 8);
            short8 a2 = *(const short8*)(Hs + ((kt + 2) * 64 + l) * 8);
            short8 a3 = *(const short8*)(Hs + ((kt + 3) * 64 + l) * 8);
            ac0 = __builtin_amdgcn_mfma_f32_16x16x32_bf16(a0, Ufrag[kt + 0], ac0, 0, 0, 0);
            ac1 = __builtin_amdgcn_mfma_f32_16x16x32_bf16(a1, Ufrag[kt + 1], ac1, 0, 0, 0);
            ac2 = __builtin_amdgcn_mfma_f32_16x16x32_bf16(a2, Ufrag[kt + 2], ac2, 0, 0, 0);
            ac3 = __builtin_amdgcn_mfma_f32_16x16x32_bf16(a3, Ufrag[kt + 3], ac3, 0, 0, 0);
        }
        f32x4 acc = (ac0 + ac1) + (ac2 + ac3);

#pragma unroll
        for (int r = 0; r < 4; ++r)
            zbuf[(g * 16 + rb0 + r) * 17 + zc] = acc[r] + xv[r];
        __syncthreads();                     // barrier 2 (also: Hs reads done)

        {   // gate combine (thread owns (bl, ul))
            float zi = zbuf[(0 * 16 + bl) * 17 + ul];
            float zf = zbuf[(1 * 16 + bl) * 17 + ul];
            float zg = zbuf[(2 * 16 + bl) * 17 + ul];
            float zo = zbuf[(3 * 16 + bl) * 17 + ul];
            float gi = sigmoidf(zi), gf = sigmoidf(zf);
            float gg = sigmoidf(zg), go = sigmoidf(zo);
            c_reg = gf * c_reg + gi * gg;
            float h = go * sigmoidf(c_reg);
            // critical-path publish FIRST (fire-and-forget into slot s+1)
            unsigned short mybf = f2bf(h);
            unsigned short obf = (unsigned short)__shfl_xor((int)mybf, 1, 64);
            if ((ul & 1) == 0) {
                int kt = u >> 5, grp = (u >> 3) & 3, j = u & 7;
                int fidx = (kt * 64 + grp * 16 + bl) * 8 + j;
                store_dword_sc(&hring[((size_t)(s + 1) * 4 + p) * 8192 + (fidx >> 1)],
                               (unsigned int)mybf | ((unsigned int)obf << 16));
            }
            outO[((size_t)b * NT + s) * NU + u] = h;          // plain store
            if (s == NT - 1) {
                outH[(size_t)b * NU + u] = h;
                outC[(size_t)b * NU + u] = c_reg;
            }
        }
        // no end-of-step barrier, no vm drain: next iteration's Hs write is
        // already gated by barrier 2, and h stores self-announce via sentinels
    }
}

// ---------- legacy scan (flags + barriers) — fallback when ws too small ----------
__global__ void __launch_bounds__(256, 1) scan_kernel(
    const unsigned short* __restrict__ UT,
    const unsigned short* __restrict__ XZ,
    const float* __restrict__ h0, const float* __restrict__ c0,
    unsigned int* hbuf32, unsigned int* flags, float* __restrict__ out) {
    extern __shared__ unsigned char smem[];
    unsigned short* Hs = (unsigned short*)smem;
    unsigned int* Hs32 = (unsigned int*)smem;
    float* zbuf = (float*)(smem + 32768);

    const int wg = blockIdx.x;
    const int p = wg >> 6, q = wg & 63;
    const int tid = threadIdx.x;
    const int g = tid >> 6;
    const int l = tid & 63;

    short8 Ufrag[32];
    {
        const unsigned short* urow =
            UT + ((size_t)(g * NU + q * 16 + (l & 15))) * NU + (l >> 4) * 8;
#pragma unroll
        for (int kt = 0; kt < 32; ++kt)
            Ufrag[kt] = *(const short8*)(urow + kt * 32);
    }

    const int bl = tid >> 4, ul = tid & 15;
    const int b = p * 16 + bl, u = q * 16 + ul;
    float c_reg = c0[(size_t)b * NU + u];
    {
        float hv = h0[(size_t)b * NU + u];
        unsigned short mybf = f2bf(hv);
        unsigned short obf = (unsigned short)__shfl_xor((int)mybf, 1, 64);
        if ((ul & 1) == 0) {
            int kt = u >> 5, grp = (u >> 3) & 3, j = u & 7;
            int fidx = (kt * 64 + grp * 16 + bl) * 8 + j;
            store_dword_sc(&hbuf32[(size_t)p * 8192 + (fidx >> 1)],
                           (unsigned int)mybf | ((unsigned int)obf << 16));
        }
    }
    wait_vm0();
    __syncthreads();
    if (tid == 0) store_dword_sc(&flags[wg], 1u);

    const unsigned short* xz_base = XZ + (size_t)(p * 16) * NT * NG + (size_t)(g * NU + q * 16);
    const int rb0 = (l >> 4) * 4, zc = l & 15;
    float* outO = out;
    float* outH = out + (size_t)NB * NT * NU;
    float* outC = outH + (size_t)NB * NU;

    for (int s = 0; s < NT; ++s) {
        float xv[4];
#pragma unroll
        for (int r = 0; r < 4; ++r)
            xv[r] = bf2f(xz_base[(size_t)((rb0 + r) * NT + s) * NG + zc]);

        if (tid < 64) {
            const unsigned int target = (unsigned int)(s + 1);
            const unsigned int* fl = &flags[p * 64 + tid];
            while (load_dword_sc_wait(fl) < target) { }
        }
        __syncthreads();

        {
            const unsigned int* hb = hbuf32 + (size_t)((s & 1) * 4 + p) * 8192;
            u32x4 t[8];
#pragma unroll
            for (int k = 0; k < 8; ++k)
                t[k] = load_b128_sc(hb + k * 1024 + tid * 4);
            wait_vm0();
            __builtin_amdgcn_sched_barrier(0);
#pragma unroll
            for (int k = 0; k < 8; ++k)
                *(u32x4*)(Hs32 + k * 1024 + tid * 4) = t[k];
        }
        __syncthreads();

        f32x4 ac0 = f32x4{0.f, 0.f, 0.f, 0.f}, ac1 = ac0, ac2 = ac0, ac3 = ac0;
#pragma unroll
        for (int kt = 0; kt < 32; kt += 4) {
            short8 a0 = *(const short8*)(Hs + ((kt + 0) * 64 + l) * 8);
            short8 a1 = *(const short8*)(Hs + ((kt + 1) * 64 + l) * 8);
            short8 a2 = *(const short8*)(Hs + ((kt + 2) * 64 + l) * 8);
            short8 a3 = *(const short8*)(Hs + ((kt + 3) * 64 + l) * 8);
            ac0 = __builtin_amdgcn_mfma_f32_16x16x32_bf16(a0, Ufrag[kt + 0], ac0, 0, 0, 0);
            ac1 = __builtin_amdgcn_mfma_f32_16x16x32_bf16(a1, Ufrag[kt + 1], ac1, 0, 0, 0);
            ac2 = __builtin_amdgcn_mfma_f32_16x16x32_bf16(a2, Ufrag[kt + 2], ac2, 0, 0, 0);
            ac3 = __builtin_amdgcn_mfma_f32_16x16x32_bf16(a3, Ufrag[kt + 3], ac3, 0, 0, 0);
        }
        f32x4 acc = (ac0 + ac1) + (ac2 + ac3);

#pragma unroll
        for (int r = 0; r < 4; ++r)
            zbuf[(g * 16 + rb0 + r) * 17 + zc] = acc[r] + xv[r];
        __syncthreads();
        {
            float zi = zbuf[(0 * 16 + bl) * 17 + ul];
            float zf = zbuf[(1 * 16 + bl) * 17 + ul];
            float zg = zbuf[(2 * 16 + bl) * 17 + ul];
            float zo = zbuf[(3 * 16 + bl) * 17 + ul];
            float gi = sigmoidf(zi), gf = sigmoidf(zf);
            float gg = sigmoidf(zg), go = sigmoidf(zo);
            c_reg = gf * c_reg + gi * gg;
            float h = go * sigmoidf(c_reg);
            outO[((size_t)b * NT + s) * NU + u] = h;
            unsigned short mybf = f2bf(h);
            unsigned short obf = (unsigned short)__shfl_xor((int)mybf, 1, 64);
            if ((ul & 1) == 0) {
                int kt = u >> 5, grp = (u >> 3) & 3, j = u & 7;
                int fidx = (kt * 64 + grp * 16 + bl) * 8 + j;
                store_dword_sc(&hbuf32[(size_t)(((s + 1) & 1) * 4 + p) * 8192 + (fidx >> 1)],
                               (unsigned int)mybf | ((unsigned int)obf << 16));
            }
            if (s == NT - 1) {
                outH[(size_t)b * NU + u] = h;
                outC[(size_t)b * NU + u] = c_reg;
            }
        }
        wait_vm0();
        __syncthreads();
        if (tid == 0)
            store_dword_sc(&flags[wg], (unsigned int)(s + 2));
    }
}

extern "C" void kernel_launch(void* const* d_in, const int* in_sizes, int n_in,
                              void* d_out, int out_size, void* d_ws, size_t ws_size,
                              hipStream_t stream) {
    const int* tokens = (const int*)d_in[0];
    const float* h0 = (const float*)d_in[1];
    const float* c0 = (const float*)d_in[2];
    const float* emb = (const float*)d_in[3];
    const float* W = (const float*)d_in[4];
    const float* U = (const float*)d_in[5];
    const float* bias = (const float*)d_in[6];
    float* out = (float*)d_out;

    unsigned char* ws = (unsigned char*)d_ws;
    unsigned short* em_bf = (unsigned short*)(ws + WS_EM);
    unsigned short* WT = (unsigned short*)(ws + WS_WT);
    unsigned short* UT = (unsigned short*)(ws + WS_UT);
    unsigned short* XZ = (unsigned short*)(ws + WS_XZ);
    unsigned int* hbuf32 = (unsigned int*)(ws + WS_HBUF);
    unsigned int* flags = (unsigned int*)(ws + WS_FLAGS);
    unsigned int* hring = (unsigned int*)(ws + WS_RING);

    const bool use_ring = ws_size >= WS_RING + RING_BYTES;

    // W [512][4096] -> WT [4096][512] bf16
    transpose_cast_kernel<<<dim3(NE / 32, NG / 32), 256, 0, stream>>>(W, (unsigned int*)WT, NE, NG);
    // U [1024][4096] -> UT [4096][1024] bf16
    transpose_cast_kernel<<<dim3(NU / 32, NG / 32), 256, 0, stream>>>(U, (unsigned int*)UT, NU, NG);
    gather_kernel<<<ROWS, 256, 0, stream>>>(tokens, emb, (unsigned int*)em_bf);
    gemm1_kernel<<<4096, 256, 0, stream>>>(em_bf, WT, bias, XZ);

    if (use_ring) {
        fill_ring_kernel<<<2048, 256, 0, stream>>>(hring, RING_DWORDS / 4);
        hipFuncSetAttribute((const void*)scan_ring_kernel,
                            hipFuncAttributeMaxDynamicSharedMemorySize, SCAN_LDS_BYTES);
        scan_ring_kernel<<<256, 256, SCAN_LDS_BYTES, stream>>>(UT, XZ, h0, c0, hring, out);
    } else {
        hipMemsetAsync(flags, 0, 1024, stream);
        hipFuncSetAttribute((const void*)scan_kernel,
                            hipFuncAttributeMaxDynamicSharedMemorySize, SCAN_LDS_BYTES);
        scan_kernel<<<256, 256, SCAN_LDS_BYTES, stream>>>(UT, XZ, h0, c0, hbuf32, flags, out);
    }
}